// Round 1
// baseline (1475.474 us; speedup 1.0000x reference)
//
#include <hip/hip_runtime.h>

// Problem constants (verified against in_sizes at runtime where cheap)
#define ND 128      // model dim D
#define NH 8        // heads
#define DHD 16      // head dim

// ---------------------------------------------------------------------------
// Tiny kernel: per-head column sums of W_pd / W_pm and bias sums.
// wpd/wpm layout: [k][h] -> k*8+h  (k = input dim 0..127, h = head 0..7)
// ---------------------------------------------------------------------------
__global__ void k_wsum(const float* __restrict__ Wpd, const float* __restrict__ bpd,
                       const float* __restrict__ Wpm, const float* __restrict__ bpm,
                       float* __restrict__ wpd, float* __restrict__ wpm,
                       float* __restrict__ bs) {
  int t = blockIdx.x * blockDim.x + threadIdx.x;
  if (t < 1024) {
    int k = t >> 3, h = t & 7;
    float s = 0.f;
#pragma unroll
    for (int d = 0; d < 16; ++d) s += Wpd[k * 128 + h * 16 + d];
    wpd[t] = s;
  } else if (t < 2048) {
    int u = t - 1024, k = u >> 3, h = u & 7;
    float s = 0.f;
#pragma unroll
    for (int d = 0; d < 16; ++d) s += Wpm[k * 128 + h * 16 + d];
    wpm[u] = s;
  } else if (t < 2056) {
    int h = t - 2048;
    float s = 0.f;
#pragma unroll
    for (int d = 0; d < 16; ++d) s += bpd[h * 16 + d] + bpm[h * 16 + d];
    bs[h] = s;
  }
}

// ---------------------------------------------------------------------------
// Generic row-block GEMM: Y[n,CO] = X[n,CI] @ W[CI,CO] + B, optional ReLU.
// Block = CO threads, 8 rows per block. W rows streamed (L2-resident).
// ---------------------------------------------------------------------------
template <int CI, int CO, bool RELU>
__global__ __launch_bounds__(CO) void k_gemm_bias(const float* __restrict__ X,
                                                  const float* __restrict__ W,
                                                  const float* __restrict__ B,
                                                  float* __restrict__ Y, int n) {
  __shared__ float xs[8][CI];
  const int c = threadIdx.x;
  const int r0 = blockIdx.x * 8;
  const int nr = min(8, n - r0);
  for (int i = c; i < nr * CI; i += CO) xs[i / CI][i % CI] = X[r0 * CI + i];
  __syncthreads();
  float acc[8];
#pragma unroll
  for (int r = 0; r < 8; ++r) acc[r] = 0.f;
  for (int k = 0; k < CI; ++k) {
    float w = W[k * CO + c];
#pragma unroll
    for (int r = 0; r < 8; ++r) acc[r] += xs[r][k] * w;
  }
  const float b = B[c];
  for (int r = 0; r < nr; ++r) {
    float v = acc[r] + b;
    if (RELU) v = fmaxf(v, 0.f);
    Y[(size_t)(r0 + r) * CO + c] = v;
  }
}

// ---------------------------------------------------------------------------
// Edge bias-score kernel: esum[e][h] = de[e,:].wpd[:,h] + m[e,:].wpm[:,h] + bs[h]
// One wave per edge; lane holds dims {2l, 2l+1}; batched butterfly reduce.
// ---------------------------------------------------------------------------
__global__ __launch_bounds__(256) void k_esum(const float* __restrict__ de,
                                              const float* __restrict__ m,
                                              const float* __restrict__ wpd,
                                              const float* __restrict__ wpm,
                                              const float* __restrict__ bs,
                                              float* __restrict__ esum, int E_) {
  const int lane = threadIdx.x & 63;
  const int d0 = lane << 1;
  float a0[8], a1[8], b0[8], b1[8];
#pragma unroll
  for (int h = 0; h < 8; ++h) {
    a0[h] = wpd[d0 * 8 + h];
    a1[h] = wpd[(d0 + 1) * 8 + h];
    b0[h] = wpm[d0 * 8 + h];
    b1[h] = wpm[(d0 + 1) * 8 + h];
  }
  const float bv = (lane < 8) ? bs[lane] : 0.f;
  const int nw = (gridDim.x * blockDim.x) >> 6;
  for (int e = (blockIdx.x * blockDim.x + threadIdx.x) >> 6; e < E_; e += nw) {
    const float2 dv = *(const float2*)(de + (size_t)e * 128 + d0);
    const float2 mv = *(const float2*)(m + (size_t)e * 128 + d0);
    float p[8];
#pragma unroll
    for (int h = 0; h < 8; ++h)
      p[h] = dv.x * a0[h] + dv.y * a1[h] + mv.x * b0[h] + mv.y * b1[h];
#pragma unroll
    for (int st = 1; st < 64; st <<= 1) {
#pragma unroll
      for (int h = 0; h < 8; ++h) p[h] += __shfl_xor(p[h], st);
    }
    float v = p[0];
#pragma unroll
    for (int h = 1; h < 8; ++h) v = (lane == h) ? p[h] : v;
    if (lane < 8) esum[(size_t)e * 8 + lane] = v + bv;
  }
}

// ---------------------------------------------------------------------------
// Edge attention kernel: one wave per edge.
// qk per head via 8-lane segment reduce; s = exp(clip(4*qk + esum, -5, 5));
// scatter V[src]*s and z with global f32 atomics.
// ---------------------------------------------------------------------------
__global__ __launch_bounds__(256) void k_edge(const float* __restrict__ Q,
                                              const float* __restrict__ K,
                                              const float* __restrict__ V,
                                              const float* __restrict__ esum,
                                              const int* __restrict__ src,
                                              const int* __restrict__ dst,
                                              float* __restrict__ wV,
                                              float* __restrict__ z, int E_) {
  const int e = (blockIdx.x * blockDim.x + threadIdx.x) >> 6;
  if (e >= E_) return;
  const int lane = threadIdx.x & 63;
  const int sn = src[e];
  const int dn = dst[e];
  const int d0 = lane << 1;
  const int h = lane >> 3;
  const float2 k2 = *(const float2*)(K + (size_t)sn * 128 + d0);
  const float2 q2 = *(const float2*)(Q + (size_t)dn * 128 + d0);
  float qk = k2.x * q2.x + k2.y * q2.y;
  qk += __shfl_xor(qk, 1);
  qk += __shfl_xor(qk, 2);
  qk += __shfl_xor(qk, 4);
  float sc = 4.f * qk + esum[(size_t)e * 8 + h];
  sc = fminf(5.f, fmaxf(-5.f, sc));
  const float s = expf(sc);
  const float2 v2 = *(const float2*)(V + (size_t)sn * 128 + d0);
  atomicAdd(wV + (size_t)dn * 128 + d0, v2.x * s);
  atomicAdd(wV + (size_t)dn * 128 + d0 + 1, v2.y * s);
  if ((lane & 7) == 0) atomicAdd(z + (size_t)dn * 8 + h, s);
}

// ---------------------------------------------------------------------------
// attn normalize + I @ W_i + b_i  -> T[n,128]
// ---------------------------------------------------------------------------
__global__ __launch_bounds__(128) void k_attn_combine(const float* __restrict__ I_,
                                                      const float* __restrict__ Wi,
                                                      const float* __restrict__ bi,
                                                      const float* __restrict__ wV,
                                                      const float* __restrict__ z,
                                                      float* __restrict__ T, int n) {
  __shared__ float xs[8][64];
  const int c = threadIdx.x;
  const int r0 = blockIdx.x * 8;
  const int nr = min(8, n - r0);
  for (int i = c; i < nr * 64; i += 128) xs[i >> 6][i & 63] = I_[r0 * 64 + i];
  __syncthreads();
  float acc[8];
#pragma unroll
  for (int r = 0; r < 8; ++r) acc[r] = 0.f;
  for (int k = 0; k < 64; ++k) {
    float w = Wi[k * 128 + c];
#pragma unroll
    for (int r = 0; r < 8; ++r) acc[r] += xs[r][k] * w;
  }
  const float b = bi[c];
  const int hh = c >> 4;
  for (int r = 0; r < nr; ++r) {
    const size_t row = r0 + r;
    const float attn = wV[row * 128 + c] / (z[row * 8 + hh] + 1e-10f);
    T[row * 128 + c] = attn + acc[r] + b;
  }
}

// ---------------------------------------------------------------------------
// GEMM (CI->128) + bias + residual + LayerNorm + eval-BatchNorm, fused.
// Block = 128 threads, 8 rows/block.
// ---------------------------------------------------------------------------
template <int CI>
__global__ __launch_bounds__(128) void k_gemm_ln(const float* __restrict__ X,
                                                 const float* __restrict__ W,
                                                 const float* __restrict__ B,
                                                 const float* __restrict__ RES,
                                                 const float* __restrict__ lng,
                                                 const float* __restrict__ lnb,
                                                 const float* __restrict__ bng,
                                                 const float* __restrict__ bnb,
                                                 float* __restrict__ Y, int n) {
  __shared__ float xs[8][CI];
  __shared__ float ys[8][128];
  __shared__ float mu_s[8], rs_s[8];
  const int c = threadIdx.x;
  const int r0 = blockIdx.x * 8;
  const int nr = min(8, n - r0);
  for (int i = c; i < nr * CI; i += 128) xs[i / CI][i % CI] = X[(size_t)r0 * CI + i];
  __syncthreads();
  float acc[8];
#pragma unroll
  for (int r = 0; r < 8; ++r) acc[r] = 0.f;
  for (int k = 0; k < CI; ++k) {
    float w = W[k * 128 + c];
#pragma unroll
    for (int r = 0; r < 8; ++r) acc[r] += xs[r][k] * w;
  }
  const float b = B[c];
  for (int r = 0; r < nr; ++r)
    ys[r][c] = acc[r] + b + RES[(size_t)(r0 + r) * 128 + c];
  __syncthreads();
  // stats: 8 groups of 16 threads, group g handles row g
  const int gr = c >> 4, j = c & 15;
  float s1 = 0.f, s2 = 0.f;
#pragma unroll
  for (int i = 0; i < 8; ++i) {
    float v = ys[gr][j + 16 * i];
    s1 += v;
    s2 += v * v;
  }
#pragma unroll
  for (int st = 1; st < 16; st <<= 1) {
    s1 += __shfl_xor(s1, st);
    s2 += __shfl_xor(s2, st);
  }
  if (j == 0) {
    const float mu = s1 * (1.f / 128.f);
    const float var = s2 * (1.f / 128.f) - mu * mu;
    mu_s[gr] = mu;
    rs_s[gr] = rsqrtf(var + 1e-5f);
  }
  __syncthreads();
  const float bnscale = rsqrtf(1.f + 1e-5f);
  const float g_c = lng[c], lb_c = lnb[c], bg_c = bng[c] * bnscale, bb_c = bnb[c];
  for (int r = 0; r < nr; ++r) {
    const float v = ys[r][c];
    const float t = (v - mu_s[r]) * rs_s[r] * g_c + lb_c;
    Y[(size_t)(r0 + r) * 128 + c] = t * bg_c + bb_c;
  }
}

// ---------------------------------------------------------------------------
extern "C" void kernel_launch(void* const* d_in, const int* in_sizes, int n_in,
                              void* d_out, int out_size, void* d_ws, size_t ws_size,
                              hipStream_t stream) {
  const float* h_   = (const float*)d_in[0];
  const float* de   = (const float*)d_in[1];
  const float* m_   = (const float*)d_in[2];
  const float* I_   = (const float*)d_in[3];
  const float* W_Q  = (const float*)d_in[4];
  const float* b_Q  = (const float*)d_in[5];
  const float* W_K  = (const float*)d_in[6];
  const float* b_K  = (const float*)d_in[7];
  const float* W_V  = (const float*)d_in[8];
  const float* b_V  = (const float*)d_in[9];
  const float* W_pd = (const float*)d_in[10];
  const float* b_pd = (const float*)d_in[11];
  const float* W_pm = (const float*)d_in[12];
  const float* b_pm = (const float*)d_in[13];
  const float* W_i  = (const float*)d_in[14];
  const float* b_i  = (const float*)d_in[15];
  const float* W_O  = (const float*)d_in[16];
  const float* b_O  = (const float*)d_in[17];
  const float* ln1g = (const float*)d_in[18];
  const float* ln1b = (const float*)d_in[19];
  const float* bn1g = (const float*)d_in[20];
  const float* bn1b = (const float*)d_in[21];
  const float* W_f1 = (const float*)d_in[22];
  const float* b_f1 = (const float*)d_in[23];
  const float* W_f2 = (const float*)d_in[24];
  const float* b_f2 = (const float*)d_in[25];
  const float* ln2g = (const float*)d_in[26];
  const float* ln2b = (const float*)d_in[27];
  const float* bn2g = (const float*)d_in[28];
  const float* bn2b = (const float*)d_in[29];
  const int* src    = (const int*)d_in[30];
  const int* dst    = (const int*)d_in[31];

  const int N_ = in_sizes[0] / 128;   // 50000
  const int E_ = in_sizes[30];        // 800000
  const size_t ND_ = (size_t)N_ * 128;

  float* ws = (float*)d_ws;
  size_t off = 0;
  float* Qb   = ws + off; off += ND_;
  float* Kb   = ws + off; off += ND_;
  float* Vb   = ws + off; off += ND_;
  float* wV   = ws + off; off += ND_;
  float* zb   = ws + off; off += (size_t)N_ * 8;
  float* esum = ws + off; off += (size_t)E_ * 8;
  float* Tb   = ws + off; off += ND_;
  float* h2   = ws + off; off += ND_;
  float* hid  = ws + off; off += (size_t)N_ * 256;
  float* wpd  = ws + off; off += 1024;
  float* wpm  = ws + off; off += 1024;
  float* bs   = ws + off; off += 8;
  (void)ws_size; (void)n_in; (void)out_size;

  float* out = (float*)d_out;

  const int nrb = (N_ + 7) / 8;

  // 1. weight head-sums
  k_wsum<<<9, 256, 0, stream>>>(W_pd, b_pd, W_pm, b_pm, wpd, wpm, bs);

  // 2. Q, K, V projections
  k_gemm_bias<128, 128, false><<<nrb, 128, 0, stream>>>(h_, W_Q, b_Q, Qb, N_);
  k_gemm_bias<128, 128, false><<<nrb, 128, 0, stream>>>(h_, W_K, b_K, Kb, N_);
  k_gemm_bias<128, 128, false><<<nrb, 128, 0, stream>>>(h_, W_V, b_V, Vb, N_);

  // 3. edge bias scores (memory-bound on de + m)
  k_esum<<<4096, 256, 0, stream>>>(de, m_, wpd, wpm, bs, esum, E_);

  // 4. zero accumulators (wV and z are adjacent)
  hipMemsetAsync(wV, 0, (ND_ + (size_t)N_ * 8) * sizeof(float), stream);

  // 5. edge attention scatter
  {
    const int waves = E_;
    const int blocks = (waves * 64 + 255) / 256;
    k_edge<<<blocks, 256, 0, stream>>>(Qb, Kb, Vb, esum, src, dst, wV, zb, E_);
  }

  // 6. attn normalize + I @ W_i
  k_attn_combine<<<nrb, 128, 0, stream>>>(I_, W_i, b_i, wV, zb, Tb, N_);

  // 7. W_O + residual(h) + LN1 + BN1 -> h2
  k_gemm_ln<128><<<nrb, 128, 0, stream>>>(Tb, W_O, b_O, h_, ln1g, ln1b, bn1g, bn1b, h2, N_);

  // 8. FFN1 (ReLU)
  k_gemm_bias<128, 256, true><<<nrb, 256, 0, stream>>>(h2, W_f1, b_f1, hid, N_);

  // 9. FFN2 + residual(h2) + LN2 + BN2 -> out
  k_gemm_ln<256><<<nrb, 128, 0, stream>>>(hid, W_f2, b_f2, h2, ln2g, ln2b, bn2g, bn2b, out, N_);
}

// Round 2
// 1097.216 us; speedup vs baseline: 1.3447x; 1.3447x over previous
//
#include <hip/hip_runtime.h>

// Problem constants
#define ND 128      // model dim D
#define NH 8        // heads
#define DHD 16      // head dim

// ---------------------------------------------------------------------------
// Tiny kernel: per-head column sums of W_pd / W_pm and bias sums.
// wpd/wpm layout: [k][h] -> k*8+h
// ---------------------------------------------------------------------------
__global__ void k_wsum(const float* __restrict__ Wpd, const float* __restrict__ bpd,
                       const float* __restrict__ Wpm, const float* __restrict__ bpm,
                       float* __restrict__ wpd, float* __restrict__ wpm,
                       float* __restrict__ bs) {
  int t = blockIdx.x * blockDim.x + threadIdx.x;
  if (t < 1024) {
    int k = t >> 3, h = t & 7;
    float s = 0.f;
#pragma unroll
    for (int d = 0; d < 16; ++d) s += Wpd[k * 128 + h * 16 + d];
    wpd[t] = s;
  } else if (t < 2048) {
    int u = t - 1024, k = u >> 3, h = u & 7;
    float s = 0.f;
#pragma unroll
    for (int d = 0; d < 16; ++d) s += Wpm[k * 128 + h * 16 + d];
    wpm[u] = s;
  } else if (t < 2056) {
    int h = t - 2048;
    float s = 0.f;
#pragma unroll
    for (int d = 0; d < 16; ++d) s += bpd[h * 16 + d] + bpm[h * 16 + d];
    bs[h] = s;
  }
}

// ---------------------------------------------------------------------------
// Generic row-block GEMM: Y[n,CO] = X[n,CI] @ W[CI,CO] + B, optional ReLU.
// ---------------------------------------------------------------------------
template <int CI, int CO, bool RELU>
__global__ __launch_bounds__(CO) void k_gemm_bias(const float* __restrict__ X,
                                                  const float* __restrict__ W,
                                                  const float* __restrict__ B,
                                                  float* __restrict__ Y, int n) {
  __shared__ float xs[8][CI];
  const int c = threadIdx.x;
  const int r0 = blockIdx.x * 8;
  const int nr = min(8, n - r0);
  for (int i = c; i < nr * CI; i += CO) xs[i / CI][i % CI] = X[r0 * CI + i];
  __syncthreads();
  float acc[8];
#pragma unroll
  for (int r = 0; r < 8; ++r) acc[r] = 0.f;
  for (int k = 0; k < CI; ++k) {
    float w = W[k * CO + c];
#pragma unroll
    for (int r = 0; r < 8; ++r) acc[r] += xs[r][k] * w;
  }
  const float b = B[c];
  for (int r = 0; r < nr; ++r) {
    float v = acc[r] + b;
    if (RELU) v = fmaxf(v, 0.f);
    Y[(size_t)(r0 + r) * CO + c] = v;
  }
}

// ---------------------------------------------------------------------------
// Edge bias-score kernel: esum[e][h] = de[e,:].wpd[:,h] + m[e,:].wpm[:,h] + bs[h]
// ---------------------------------------------------------------------------
__global__ __launch_bounds__(256) void k_esum(const float* __restrict__ de,
                                              const float* __restrict__ m,
                                              const float* __restrict__ wpd,
                                              const float* __restrict__ wpm,
                                              const float* __restrict__ bs,
                                              float* __restrict__ esum, int E_) {
  const int lane = threadIdx.x & 63;
  const int d0 = lane << 1;
  float a0[8], a1[8], b0[8], b1[8];
#pragma unroll
  for (int h = 0; h < 8; ++h) {
    a0[h] = wpd[d0 * 8 + h];
    a1[h] = wpd[(d0 + 1) * 8 + h];
    b0[h] = wpm[d0 * 8 + h];
    b1[h] = wpm[(d0 + 1) * 8 + h];
  }
  const float bv = (lane < 8) ? bs[lane] : 0.f;
  const int nw = (gridDim.x * blockDim.x) >> 6;
  for (int e = (blockIdx.x * blockDim.x + threadIdx.x) >> 6; e < E_; e += nw) {
    const float2 dv = *(const float2*)(de + (size_t)e * 128 + d0);
    const float2 mv = *(const float2*)(m + (size_t)e * 128 + d0);
    float p[8];
#pragma unroll
    for (int h = 0; h < 8; ++h)
      p[h] = dv.x * a0[h] + dv.y * a1[h] + mv.x * b0[h] + mv.y * b1[h];
#pragma unroll
    for (int st = 1; st < 64; st <<= 1) {
#pragma unroll
      for (int h = 0; h < 8; ++h) p[h] += __shfl_xor(p[h], st);
    }
    float v = p[0];
#pragma unroll
    for (int h = 1; h < 8; ++h) v = (lane == h) ? p[h] : v;
    if (lane < 8) esum[(size_t)e * 8 + lane] = v + bv;
  }
}

// ---------------------------------------------------------------------------
// CSR build: histogram, scan, scatter
// ---------------------------------------------------------------------------
__global__ __launch_bounds__(256) void k_hist(const int* __restrict__ dst,
                                              int* __restrict__ counts, int E_) {
  const int i = blockIdx.x * blockDim.x + threadIdx.x;
  const int n = gridDim.x * blockDim.x;
  for (int e = i; e < E_; e += n) atomicAdd(&counts[dst[e]], 1);
}

// single-workgroup exclusive scan over N counts -> rs[N+1], cursor[N]
__global__ __launch_bounds__(1024) void k_scan(const int* __restrict__ counts,
                                               int* __restrict__ rs,
                                               int* __restrict__ cursor, int N_) {
  __shared__ int ls[1024];
  const int t = threadIdx.x;
  const int CH = (N_ + 1023) >> 10;
  const int b0 = t * CH, b1 = min(N_, b0 + CH);
  int s = 0;
  for (int i = b0; i < b1; ++i) s += counts[i];
  ls[t] = s;
  __syncthreads();
  for (int off = 1; off < 1024; off <<= 1) {
    int v = (t >= off) ? ls[t - off] : 0;
    __syncthreads();
    ls[t] += v;
    __syncthreads();
  }
  int run = ls[t] - s;  // exclusive base for this thread's chunk
  for (int i = b0; i < b1; ++i) {
    rs[i] = run;
    cursor[i] = run;
    run += counts[i];
  }
  if (t == 1023) rs[N_] = ls[1023];
}

__global__ __launch_bounds__(256) void k_scatter(const int* __restrict__ src,
                                                 const int* __restrict__ dst,
                                                 int* __restrict__ cursor,
                                                 int2* __restrict__ eidx, int E_) {
  const int i = blockIdx.x * blockDim.x + threadIdx.x;
  const int n = gridDim.x * blockDim.x;
  for (int e = i; e < E_; e += n) {
    int d = dst[e];
    int p = atomicAdd(&cursor[d], 1);
    eidx[p] = make_int2(src[e], e);
  }
}

// ---------------------------------------------------------------------------
// Gather-side attention: one wave per dst node. Q[dst] in regs; loop incoming
// edges, gather K[src]/V[src], s=exp(clip(4*qk+esum)), accumulate in regs.
// One coalesced write per node. No float atomics.
// ---------------------------------------------------------------------------
__global__ __launch_bounds__(256) void k_node_attn(const float* __restrict__ Q,
                                                   const float* __restrict__ K,
                                                   const float* __restrict__ V,
                                                   const float* __restrict__ esum,
                                                   const int* __restrict__ rs,
                                                   const int2* __restrict__ eidx,
                                                   float* __restrict__ wV,
                                                   float* __restrict__ z, int n) {
  const int node = (blockIdx.x * blockDim.x + threadIdx.x) >> 6;
  if (node >= n) return;
  const int lane = threadIdx.x & 63;
  const int d0 = lane << 1;
  const int h = lane >> 3;
  const int start = rs[node], end = rs[node + 1];
  const float2 q2 = *(const float2*)(Q + (size_t)node * 128 + d0);
  float2 acc = make_float2(0.f, 0.f);
  float zacc = 0.f;
  for (int base = start; base < end; base += 64) {
    const int nm = min(64, end - base);
    int2 meta = make_int2(0, 0);
    if (lane < nm) meta = eidx[base + lane];
    for (int j = 0; j < nm; ++j) {
      const int sn = __shfl(meta.x, j);
      const int eid = __shfl(meta.y, j);
      const float2 k2 = *(const float2*)(K + (size_t)sn * 128 + d0);
      const float2 v2 = *(const float2*)(V + (size_t)sn * 128 + d0);
      const float es = esum[(size_t)eid * 8 + h];
      float qk = k2.x * q2.x + k2.y * q2.y;
      qk += __shfl_xor(qk, 1);
      qk += __shfl_xor(qk, 2);
      qk += __shfl_xor(qk, 4);
      float sc = 4.f * qk + es;
      sc = fminf(5.f, fmaxf(-5.f, sc));
      const float s = expf(sc);
      acc.x += v2.x * s;
      acc.y += v2.y * s;
      zacc += s;
    }
  }
  *(float2*)(wV + (size_t)node * 128 + d0) = acc;
  if ((lane & 7) == 0) z[(size_t)node * 8 + h] = zacc;
}

// ---------------------------------------------------------------------------
// attn normalize + I @ W_i + b_i  -> T[n,128]
// ---------------------------------------------------------------------------
__global__ __launch_bounds__(128) void k_attn_combine(const float* __restrict__ I_,
                                                      const float* __restrict__ Wi,
                                                      const float* __restrict__ bi,
                                                      const float* __restrict__ wV,
                                                      const float* __restrict__ z,
                                                      float* __restrict__ T, int n) {
  __shared__ float xs[8][64];
  const int c = threadIdx.x;
  const int r0 = blockIdx.x * 8;
  const int nr = min(8, n - r0);
  for (int i = c; i < nr * 64; i += 128) xs[i >> 6][i & 63] = I_[r0 * 64 + i];
  __syncthreads();
  float acc[8];
#pragma unroll
  for (int r = 0; r < 8; ++r) acc[r] = 0.f;
  for (int k = 0; k < 64; ++k) {
    float w = Wi[k * 128 + c];
#pragma unroll
    for (int r = 0; r < 8; ++r) acc[r] += xs[r][k] * w;
  }
  const float b = bi[c];
  const int hh = c >> 4;
  for (int r = 0; r < nr; ++r) {
    const size_t row = r0 + r;
    const float attn = wV[row * 128 + c] / (z[row * 8 + hh] + 1e-10f);
    T[row * 128 + c] = attn + acc[r] + b;
  }
}

// ---------------------------------------------------------------------------
// GEMM (CI->128) + bias + residual + LayerNorm + eval-BatchNorm, fused.
// ---------------------------------------------------------------------------
template <int CI>
__global__ __launch_bounds__(128) void k_gemm_ln(const float* __restrict__ X,
                                                 const float* __restrict__ W,
                                                 const float* __restrict__ B,
                                                 const float* __restrict__ RES,
                                                 const float* __restrict__ lng,
                                                 const float* __restrict__ lnb,
                                                 const float* __restrict__ bng,
                                                 const float* __restrict__ bnb,
                                                 float* __restrict__ Y, int n) {
  __shared__ float xs[8][CI];
  __shared__ float ys[8][128];
  __shared__ float mu_s[8], rs_s[8];
  const int c = threadIdx.x;
  const int r0 = blockIdx.x * 8;
  const int nr = min(8, n - r0);
  for (int i = c; i < nr * CI; i += 128) xs[i / CI][i % CI] = X[(size_t)r0 * CI + i];
  __syncthreads();
  float acc[8];
#pragma unroll
  for (int r = 0; r < 8; ++r) acc[r] = 0.f;
  for (int k = 0; k < CI; ++k) {
    float w = W[k * 128 + c];
#pragma unroll
    for (int r = 0; r < 8; ++r) acc[r] += xs[r][k] * w;
  }
  const float b = B[c];
  for (int r = 0; r < nr; ++r)
    ys[r][c] = acc[r] + b + RES[(size_t)(r0 + r) * 128 + c];
  __syncthreads();
  const int gr = c >> 4, j = c & 15;
  float s1 = 0.f, s2 = 0.f;
#pragma unroll
  for (int i = 0; i < 8; ++i) {
    float v = ys[gr][j + 16 * i];
    s1 += v;
    s2 += v * v;
  }
#pragma unroll
  for (int st = 1; st < 16; st <<= 1) {
    s1 += __shfl_xor(s1, st);
    s2 += __shfl_xor(s2, st);
  }
  if (j == 0) {
    const float mu = s1 * (1.f / 128.f);
    const float var = s2 * (1.f / 128.f) - mu * mu;
    mu_s[gr] = mu;
    rs_s[gr] = rsqrtf(var + 1e-5f);
  }
  __syncthreads();
  const float bnscale = rsqrtf(1.f + 1e-5f);
  const float g_c = lng[c], lb_c = lnb[c], bg_c = bng[c] * bnscale, bb_c = bnb[c];
  for (int r = 0; r < nr; ++r) {
    const float v = ys[r][c];
    const float t = (v - mu_s[r]) * rs_s[r] * g_c + lb_c;
    Y[(size_t)(r0 + r) * 128 + c] = t * bg_c + bb_c;
  }
}

// ---------------------------------------------------------------------------
extern "C" void kernel_launch(void* const* d_in, const int* in_sizes, int n_in,
                              void* d_out, int out_size, void* d_ws, size_t ws_size,
                              hipStream_t stream) {
  const float* h_   = (const float*)d_in[0];
  const float* de   = (const float*)d_in[1];
  const float* m_   = (const float*)d_in[2];
  const float* I_   = (const float*)d_in[3];
  const float* W_Q  = (const float*)d_in[4];
  const float* b_Q  = (const float*)d_in[5];
  const float* W_K  = (const float*)d_in[6];
  const float* b_K  = (const float*)d_in[7];
  const float* W_V  = (const float*)d_in[8];
  const float* b_V  = (const float*)d_in[9];
  const float* W_pd = (const float*)d_in[10];
  const float* b_pd = (const float*)d_in[11];
  const float* W_pm = (const float*)d_in[12];
  const float* b_pm = (const float*)d_in[13];
  const float* W_i  = (const float*)d_in[14];
  const float* b_i  = (const float*)d_in[15];
  const float* W_O  = (const float*)d_in[16];
  const float* b_O  = (const float*)d_in[17];
  const float* ln1g = (const float*)d_in[18];
  const float* ln1b = (const float*)d_in[19];
  const float* bn1g = (const float*)d_in[20];
  const float* bn1b = (const float*)d_in[21];
  const float* W_f1 = (const float*)d_in[22];
  const float* b_f1 = (const float*)d_in[23];
  const float* W_f2 = (const float*)d_in[24];
  const float* b_f2 = (const float*)d_in[25];
  const float* ln2g = (const float*)d_in[26];
  const float* ln2b = (const float*)d_in[27];
  const float* bn2g = (const float*)d_in[28];
  const float* bn2b = (const float*)d_in[29];
  const int* src    = (const int*)d_in[30];
  const int* dst    = (const int*)d_in[31];

  const int N_ = in_sizes[0] / 128;   // 50000
  const int E_ = in_sizes[30];        // 800000
  const size_t ND_ = (size_t)N_ * 128;

  float* ws = (float*)d_ws;
  size_t off = 0;
  float* Qb   = ws + off; off += ND_;
  float* Kb   = ws + off; off += ND_;
  float* Vb   = ws + off; off += ND_;
  float* wV   = ws + off; off += ND_;
  float* zb   = ws + off; off += (size_t)N_ * 8;
  float* esum = ws + off; off += (size_t)E_ * 8;
  float* Tb   = ws + off; off += ND_;
  float* h2   = ws + off; off += ND_;
  float* hid  = ws + off; off += (size_t)N_ * 256;   // FFN scratch; CSR aliased here
  float* wpd  = ws + off; off += 1024;
  float* wpm  = ws + off; off += 1024;
  float* bs   = ws + off; off += 8;
  (void)ws_size; (void)n_in; (void)out_size;

  // CSR arrays aliased into hid (dead until FFN stage)
  int*  rs     = (int*)hid;                  // N+1 (padded to N+2)
  int*  cursor = rs + (N_ + 2);              // N (padded to N+2)
  int2* eidx   = (int2*)(cursor + (N_ + 2)); // E entries (src, eid)

  float* out = (float*)d_out;
  const int nrb = (N_ + 7) / 8;

  // 1. weight head-sums
  k_wsum<<<9, 256, 0, stream>>>(W_pd, b_pd, W_pm, b_pm, wpd, wpm, bs);

  // 2. Q, K, V projections
  k_gemm_bias<128, 128, false><<<nrb, 128, 0, stream>>>(h_, W_Q, b_Q, Qb, N_);
  k_gemm_bias<128, 128, false><<<nrb, 128, 0, stream>>>(h_, W_K, b_K, Kb, N_);
  k_gemm_bias<128, 128, false><<<nrb, 128, 0, stream>>>(h_, W_V, b_V, Vb, N_);

  // 3. edge bias scores (memory-bound on de + m)
  k_esum<<<4096, 256, 0, stream>>>(de, m_, wpd, wpm, bs, esum, E_);

  // 4. CSR build: counts -> scan -> scatter
  hipMemsetAsync(cursor, 0, (size_t)N_ * sizeof(int), stream);  // used as counts first
  k_hist<<<1024, 256, 0, stream>>>(dst, cursor, E_);
  // scan reads cursor(=counts) and rewrites rs + cursor
  k_scan<<<1, 1024, 0, stream>>>(cursor, rs, cursor, N_);
  k_scatter<<<1024, 256, 0, stream>>>(src, dst, cursor, eidx, E_);

  // 5. gather-side attention (no atomics)
  k_node_attn<<<(N_ + 3) / 4, 256, 0, stream>>>(Qb, Kb, Vb, esum, rs, eidx, wV, zb, N_);

  // 6. attn normalize + I @ W_i
  k_attn_combine<<<nrb, 128, 0, stream>>>(I_, W_i, b_i, wV, zb, Tb, N_);

  // 7. W_O + residual(h) + LN1 + BN1 -> h2
  k_gemm_ln<128><<<nrb, 128, 0, stream>>>(Tb, W_O, b_O, h_, ln1g, ln1b, bn1g, bn1b, h2, N_);

  // 8. FFN1 (ReLU) — overwrites CSR scratch (dead by now)
  k_gemm_bias<128, 256, true><<<nrb, 256, 0, stream>>>(h2, W_f1, b_f1, hid, N_);

  // 9. FFN2 + residual(h2) + LN2 + BN2 -> out
  k_gemm_ln<256><<<nrb, 128, 0, stream>>>(hid, W_f2, b_f2, h2, ln2g, ln2b, bn2g, bn2b, out, N_);
}

// Round 3
// 891.251 us; speedup vs baseline: 1.6555x; 1.2311x over previous
//
#include <hip/hip_runtime.h>

// Problem constants
#define ND 128      // model dim D
#define NH 8        // heads
#define DHD 16      // head dim

// ---------------------------------------------------------------------------
// Tiny kernel: per-head column sums of W_pd / W_pm and bias sums.
// wpd/wpm layout: [k][h] -> k*8+h
// ---------------------------------------------------------------------------
__global__ void k_wsum(const float* __restrict__ Wpd, const float* __restrict__ bpd,
                       const float* __restrict__ Wpm, const float* __restrict__ bpm,
                       float* __restrict__ wpd, float* __restrict__ wpm,
                       float* __restrict__ bs) {
  int t = blockIdx.x * blockDim.x + threadIdx.x;
  if (t < 1024) {
    int k = t >> 3, h = t & 7;
    float s = 0.f;
#pragma unroll
    for (int d = 0; d < 16; ++d) s += Wpd[k * 128 + h * 16 + d];
    wpd[t] = s;
  } else if (t < 2048) {
    int u = t - 1024, k = u >> 3, h = u & 7;
    float s = 0.f;
#pragma unroll
    for (int d = 0; d < 16; ++d) s += Wpm[k * 128 + h * 16 + d];
    wpm[u] = s;
  } else if (t < 2056) {
    int h = t - 2048;
    float s = 0.f;
#pragma unroll
    for (int d = 0; d < 16; ++d) s += bpd[h * 16 + d] + bpm[h * 16 + d];
    bs[h] = s;
  }
}

// ---------------------------------------------------------------------------
// Generic row-block GEMM: Y[n,CO] = X[n,CI] @ W[CI,CO] + B, optional ReLU.
// ---------------------------------------------------------------------------
template <int CI, int CO, bool RELU>
__global__ __launch_bounds__(CO) void k_gemm_bias(const float* __restrict__ X,
                                                  const float* __restrict__ W,
                                                  const float* __restrict__ B,
                                                  float* __restrict__ Y, int n) {
  __shared__ float xs[8][CI];
  const int c = threadIdx.x;
  const int r0 = blockIdx.x * 8;
  const int nr = min(8, n - r0);
  for (int i = c; i < nr * CI; i += CO) xs[i / CI][i % CI] = X[r0 * CI + i];
  __syncthreads();
  float acc[8];
#pragma unroll
  for (int r = 0; r < 8; ++r) acc[r] = 0.f;
  for (int k = 0; k < CI; ++k) {
    float w = W[k * CO + c];
#pragma unroll
    for (int r = 0; r < 8; ++r) acc[r] += xs[r][k] * w;
  }
  const float b = B[c];
  for (int r = 0; r < nr; ++r) {
    float v = acc[r] + b;
    if (RELU) v = fmaxf(v, 0.f);
    Y[(size_t)(r0 + r) * CO + c] = v;
  }
}

// ---------------------------------------------------------------------------
// Edge bias-score kernel v2: LDS-tiled skinny GEMM, no cross-lane shuffles.
// Tile = 32 edges/block, 256 threads. esum[e][h] = de[e]·wpd[:,h] + m[e]·wpm[:,h] + bs[h]
// ---------------------------------------------------------------------------
__global__ __launch_bounds__(256) void k_esum2(const float* __restrict__ de,
                                               const float* __restrict__ m,
                                               const float* __restrict__ wpd,
                                               const float* __restrict__ wpm,
                                               const float* __restrict__ bs,
                                               float* __restrict__ esum, int E_) {
  __shared__ float sde[32 * 129];
  __shared__ float smm[32 * 129];
  __shared__ float swd[128 * 8];
  __shared__ float swm[128 * 8];
  __shared__ float part[8][32][8];
  const int t = threadIdx.x;
  // stage weights (broadcast-friendly [k][h] layout)
  for (int i = t; i < 1024; i += 256) { swd[i] = wpd[i]; swm[i] = wpm[i]; }
  const int e0 = blockIdx.x * 32;
  const int nr = min(32, E_ - e0);
  // stage de/m rows: 1024 float4 per array, coalesced
  if (nr == 32) {
#pragma unroll
    for (int j = 0; j < 4; ++j) {
      const int f = t + j * 256;
      const int r = f >> 5, c = (f & 31) << 2;
      const float4 v = *(const float4*)(de + (size_t)(e0 + r) * 128 + c);
      const float4 w = *(const float4*)(m + (size_t)(e0 + r) * 128 + c);
      float* pd = &sde[r * 129 + c];
      pd[0] = v.x; pd[1] = v.y; pd[2] = v.z; pd[3] = v.w;
      float* pm2 = &smm[r * 129 + c];
      pm2[0] = w.x; pm2[1] = w.y; pm2[2] = w.z; pm2[3] = w.w;
    }
  } else {
#pragma unroll
    for (int j = 0; j < 4; ++j) {
      const int f = t + j * 256;
      const int r = f >> 5, c = (f & 31) << 2;
      float4 v = make_float4(0.f, 0.f, 0.f, 0.f), w = v;
      if (r < nr) {
        v = *(const float4*)(de + (size_t)(e0 + r) * 128 + c);
        w = *(const float4*)(m + (size_t)(e0 + r) * 128 + c);
      }
      float* pd = &sde[r * 129 + c];
      pd[0] = v.x; pd[1] = v.y; pd[2] = v.z; pd[3] = v.w;
      float* pm2 = &smm[r * 129 + c];
      pm2[0] = w.x; pm2[1] = w.y; pm2[2] = w.z; pm2[3] = w.w;
    }
  }
  __syncthreads();
  // compute: thread (el, kc) covers edge el, k in [kc*16, kc*16+16)
  const int el = t & 31, kc = t >> 5;
  float acc[8];
#pragma unroll
  for (int h = 0; h < 8; ++h) acc[h] = 0.f;
  const int kbase = kc << 4;
#pragma unroll
  for (int j = 0; j < 16; ++j) {
    const int k = kbase + j;
    const float d = sde[el * 129 + k];
    const float mm = smm[el * 129 + k];
    const float4 w0 = *(const float4*)&swd[k * 8];
    const float4 w1 = *(const float4*)&swd[k * 8 + 4];
    const float4 x0 = *(const float4*)&swm[k * 8];
    const float4 x1 = *(const float4*)&swm[k * 8 + 4];
    acc[0] += d * w0.x + mm * x0.x;
    acc[1] += d * w0.y + mm * x0.y;
    acc[2] += d * w0.z + mm * x0.z;
    acc[3] += d * w0.w + mm * x0.w;
    acc[4] += d * w1.x + mm * x1.x;
    acc[5] += d * w1.y + mm * x1.y;
    acc[6] += d * w1.z + mm * x1.z;
    acc[7] += d * w1.w + mm * x1.w;
  }
  *(float4*)&part[kc][el][0] = make_float4(acc[0], acc[1], acc[2], acc[3]);
  *(float4*)&part[kc][el][4] = make_float4(acc[4], acc[5], acc[6], acc[7]);
  __syncthreads();
  // reduce partials: thread (el2, h)
  const int el2 = t >> 3, h = t & 7;
  float s = bs[h];
#pragma unroll
  for (int kk = 0; kk < 8; ++kk) s += part[kk][el2][h];
  if (el2 < nr) esum[(size_t)(e0 + el2) * 8 + h] = s;
}

// ---------------------------------------------------------------------------
// CSR build: histogram, scan, scatter
// ---------------------------------------------------------------------------
__global__ __launch_bounds__(256) void k_hist(const int* __restrict__ dst,
                                              int* __restrict__ counts, int E_) {
  const int i = blockIdx.x * blockDim.x + threadIdx.x;
  const int n = gridDim.x * blockDim.x;
  for (int e = i; e < E_; e += n) atomicAdd(&counts[dst[e]], 1);
}

// single-workgroup exclusive scan over N counts -> rs[N+1], cursor[N]
__global__ __launch_bounds__(1024) void k_scan(const int* __restrict__ counts,
                                               int* __restrict__ rs,
                                               int* __restrict__ cursor, int N_) {
  __shared__ int ls[1024];
  const int t = threadIdx.x;
  const int CH = (N_ + 1023) >> 10;
  const int b0 = t * CH, b1 = min(N_, b0 + CH);
  int s = 0;
  for (int i = b0; i < b1; ++i) s += counts[i];
  ls[t] = s;
  __syncthreads();
  for (int off = 1; off < 1024; off <<= 1) {
    int v = (t >= off) ? ls[t - off] : 0;
    __syncthreads();
    ls[t] += v;
    __syncthreads();
  }
  int run = ls[t] - s;  // exclusive base for this thread's chunk
  for (int i = b0; i < b1; ++i) {
    rs[i] = run;
    cursor[i] = run;
    run += counts[i];
  }
  if (t == 1023) rs[N_] = ls[1023];
}

__global__ __launch_bounds__(256) void k_scatter(const int* __restrict__ src,
                                                 const int* __restrict__ dst,
                                                 int* __restrict__ cursor,
                                                 int2* __restrict__ eidx, int E_) {
  const int i = blockIdx.x * blockDim.x + threadIdx.x;
  const int n = gridDim.x * blockDim.x;
  for (int e = i; e < E_; e += n) {
    int d = dst[e];
    int p = atomicAdd(&cursor[d], 1);
    eidx[p] = make_int2(src[e], e);
  }
}

// ---------------------------------------------------------------------------
// Gather-side attention: one wave per dst node. Q[dst] in regs; loop incoming
// edges, gather K[src]/V[src], s=exp(clip(4*qk+esum)), accumulate in regs.
// ---------------------------------------------------------------------------
__global__ __launch_bounds__(256) void k_node_attn(const float* __restrict__ Q,
                                                   const float* __restrict__ K,
                                                   const float* __restrict__ V,
                                                   const float* __restrict__ esum,
                                                   const int* __restrict__ rs,
                                                   const int2* __restrict__ eidx,
                                                   float* __restrict__ wV,
                                                   float* __restrict__ z, int n) {
  const int node = (blockIdx.x * blockDim.x + threadIdx.x) >> 6;
  if (node >= n) return;
  const int lane = threadIdx.x & 63;
  const int d0 = lane << 1;
  const int h = lane >> 3;
  const int start = rs[node], end = rs[node + 1];
  const float2 q2 = *(const float2*)(Q + (size_t)node * 128 + d0);
  float2 acc = make_float2(0.f, 0.f);
  float zacc = 0.f;
  for (int base = start; base < end; base += 64) {
    const int nm = min(64, end - base);
    int2 meta = make_int2(0, 0);
    if (lane < nm) meta = eidx[base + lane];
    for (int j = 0; j < nm; ++j) {
      const int sn = __shfl(meta.x, j);
      const int eid = __shfl(meta.y, j);
      const float2 k2 = *(const float2*)(K + (size_t)sn * 128 + d0);
      const float2 v2 = *(const float2*)(V + (size_t)sn * 128 + d0);
      const float es = esum[(size_t)eid * 8 + h];
      float qk = k2.x * q2.x + k2.y * q2.y;
      qk += __shfl_xor(qk, 1);
      qk += __shfl_xor(qk, 2);
      qk += __shfl_xor(qk, 4);
      float sc = 4.f * qk + es;
      sc = fminf(5.f, fmaxf(-5.f, sc));
      const float s = expf(sc);
      acc.x += v2.x * s;
      acc.y += v2.y * s;
      zacc += s;
    }
  }
  *(float2*)(wV + (size_t)node * 128 + d0) = acc;
  if ((lane & 7) == 0) z[(size_t)node * 8 + h] = zacc;
}

// ---------------------------------------------------------------------------
// attn normalize + I @ W_i + b_i  -> T[n,128]
// ---------------------------------------------------------------------------
__global__ __launch_bounds__(128) void k_attn_combine(const float* __restrict__ I_,
                                                      const float* __restrict__ Wi,
                                                      const float* __restrict__ bi,
                                                      const float* __restrict__ wV,
                                                      const float* __restrict__ z,
                                                      float* __restrict__ T, int n) {
  __shared__ float xs[8][64];
  const int c = threadIdx.x;
  const int r0 = blockIdx.x * 8;
  const int nr = min(8, n - r0);
  for (int i = c; i < nr * 64; i += 128) xs[i >> 6][i & 63] = I_[r0 * 64 + i];
  __syncthreads();
  float acc[8];
#pragma unroll
  for (int r = 0; r < 8; ++r) acc[r] = 0.f;
  for (int k = 0; k < 64; ++k) {
    float w = Wi[k * 128 + c];
#pragma unroll
    for (int r = 0; r < 8; ++r) acc[r] += xs[r][k] * w;
  }
  const float b = bi[c];
  const int hh = c >> 4;
  for (int r = 0; r < nr; ++r) {
    const size_t row = r0 + r;
    const float attn = wV[row * 128 + c] / (z[row * 8 + hh] + 1e-10f);
    T[row * 128 + c] = attn + acc[r] + b;
  }
}

// ---------------------------------------------------------------------------
// GEMM (CI->128) + bias + residual + LayerNorm + eval-BatchNorm, fused.
// ---------------------------------------------------------------------------
template <int CI>
__global__ __launch_bounds__(128) void k_gemm_ln(const float* __restrict__ X,
                                                 const float* __restrict__ W,
                                                 const float* __restrict__ B,
                                                 const float* __restrict__ RES,
                                                 const float* __restrict__ lng,
                                                 const float* __restrict__ lnb,
                                                 const float* __restrict__ bng,
                                                 const float* __restrict__ bnb,
                                                 float* __restrict__ Y, int n) {
  __shared__ float xs[8][CI];
  __shared__ float ys[8][128];
  __shared__ float mu_s[8], rs_s[8];
  const int c = threadIdx.x;
  const int r0 = blockIdx.x * 8;
  const int nr = min(8, n - r0);
  for (int i = c; i < nr * CI; i += 128) xs[i / CI][i % CI] = X[(size_t)r0 * CI + i];
  __syncthreads();
  float acc[8];
#pragma unroll
  for (int r = 0; r < 8; ++r) acc[r] = 0.f;
  for (int k = 0; k < CI; ++k) {
    float w = W[k * 128 + c];
#pragma unroll
    for (int r = 0; r < 8; ++r) acc[r] += xs[r][k] * w;
  }
  const float b = B[c];
  for (int r = 0; r < nr; ++r)
    ys[r][c] = acc[r] + b + RES[(size_t)(r0 + r) * 128 + c];
  __syncthreads();
  const int gr = c >> 4, j = c & 15;
  float s1 = 0.f, s2 = 0.f;
#pragma unroll
  for (int i = 0; i < 8; ++i) {
    float v = ys[gr][j + 16 * i];
    s1 += v;
    s2 += v * v;
  }
#pragma unroll
  for (int st = 1; st < 16; st <<= 1) {
    s1 += __shfl_xor(s1, st);
    s2 += __shfl_xor(s2, st);
  }
  if (j == 0) {
    const float mu = s1 * (1.f / 128.f);
    const float var = s2 * (1.f / 128.f) - mu * mu;
    mu_s[gr] = mu;
    rs_s[gr] = rsqrtf(var + 1e-5f);
  }
  __syncthreads();
  const float bnscale = rsqrtf(1.f + 1e-5f);
  const float g_c = lng[c], lb_c = lnb[c], bg_c = bng[c] * bnscale, bb_c = bnb[c];
  for (int r = 0; r < nr; ++r) {
    const float v = ys[r][c];
    const float t = (v - mu_s[r]) * rs_s[r] * g_c + lb_c;
    Y[(size_t)(r0 + r) * 128 + c] = t * bg_c + bb_c;
  }
}

// ---------------------------------------------------------------------------
extern "C" void kernel_launch(void* const* d_in, const int* in_sizes, int n_in,
                              void* d_out, int out_size, void* d_ws, size_t ws_size,
                              hipStream_t stream) {
  const float* h_   = (const float*)d_in[0];
  const float* de   = (const float*)d_in[1];
  const float* m_   = (const float*)d_in[2];
  const float* I_   = (const float*)d_in[3];
  const float* W_Q  = (const float*)d_in[4];
  const float* b_Q  = (const float*)d_in[5];
  const float* W_K  = (const float*)d_in[6];
  const float* b_K  = (const float*)d_in[7];
  const float* W_V  = (const float*)d_in[8];
  const float* b_V  = (const float*)d_in[9];
  const float* W_pd = (const float*)d_in[10];
  const float* b_pd = (const float*)d_in[11];
  const float* W_pm = (const float*)d_in[12];
  const float* b_pm = (const float*)d_in[13];
  const float* W_i  = (const float*)d_in[14];
  const float* b_i  = (const float*)d_in[15];
  const float* W_O  = (const float*)d_in[16];
  const float* b_O  = (const float*)d_in[17];
  const float* ln1g = (const float*)d_in[18];
  const float* ln1b = (const float*)d_in[19];
  const float* bn1g = (const float*)d_in[20];
  const float* bn1b = (const float*)d_in[21];
  const float* W_f1 = (const float*)d_in[22];
  const float* b_f1 = (const float*)d_in[23];
  const float* W_f2 = (const float*)d_in[24];
  const float* b_f2 = (const float*)d_in[25];
  const float* ln2g = (const float*)d_in[26];
  const float* ln2b = (const float*)d_in[27];
  const float* bn2g = (const float*)d_in[28];
  const float* bn2b = (const float*)d_in[29];
  const int* src    = (const int*)d_in[30];
  const int* dst    = (const int*)d_in[31];

  const int N_ = in_sizes[0] / 128;   // 50000
  const int E_ = in_sizes[30];        // 800000
  const size_t ND_ = (size_t)N_ * 128;

  float* ws = (float*)d_ws;
  size_t off = 0;
  float* Qb   = ws + off; off += ND_;
  float* Kb   = ws + off; off += ND_;
  float* Vb   = ws + off; off += ND_;
  float* wV   = ws + off; off += ND_;
  float* zb   = ws + off; off += (size_t)N_ * 8;
  float* esum = ws + off; off += (size_t)E_ * 8;
  float* Tb   = ws + off; off += ND_;
  float* h2   = ws + off; off += ND_;
  float* hid  = ws + off; off += (size_t)N_ * 256;   // FFN scratch; CSR aliased here
  float* wpd  = ws + off; off += 1024;
  float* wpm  = ws + off; off += 1024;
  float* bs   = ws + off; off += 8;
  (void)ws_size; (void)n_in; (void)out_size;

  // CSR arrays aliased into hid (dead until FFN stage)
  int*  rs     = (int*)hid;                  // N+1 (padded to N+2)
  int*  cursor = rs + (N_ + 2);              // N (padded to N+2)
  int2* eidx   = (int2*)(cursor + (N_ + 2)); // E entries (src, eid)

  float* out = (float*)d_out;
  const int nrb = (N_ + 7) / 8;

  // 1. weight head-sums
  k_wsum<<<9, 256, 0, stream>>>(W_pd, b_pd, W_pm, b_pm, wpd, wpm, bs);

  // 2. Q, K, V projections
  k_gemm_bias<128, 128, false><<<nrb, 128, 0, stream>>>(h_, W_Q, b_Q, Qb, N_);
  k_gemm_bias<128, 128, false><<<nrb, 128, 0, stream>>>(h_, W_K, b_K, Kb, N_);
  k_gemm_bias<128, 128, false><<<nrb, 128, 0, stream>>>(h_, W_V, b_V, Vb, N_);

  // 3. edge bias scores (memory-bound on de + m) — LDS-tiled, no shuffles
  k_esum2<<<(E_ + 31) / 32, 256, 0, stream>>>(de, m_, wpd, wpm, bs, esum, E_);

  // 4. CSR build: counts -> scan -> scatter
  hipMemsetAsync(cursor, 0, (size_t)N_ * sizeof(int), stream);  // used as counts first
  k_hist<<<1024, 256, 0, stream>>>(dst, cursor, E_);
  k_scan<<<1, 1024, 0, stream>>>(cursor, rs, cursor, N_);
  k_scatter<<<1024, 256, 0, stream>>>(src, dst, cursor, eidx, E_);

  // 5. gather-side attention (no atomics)
  k_node_attn<<<(N_ + 3) / 4, 256, 0, stream>>>(Qb, Kb, Vb, esum, rs, eidx, wV, zb, N_);

  // 6. attn normalize + I @ W_i
  k_attn_combine<<<nrb, 128, 0, stream>>>(I_, W_i, b_i, wV, zb, Tb, N_);

  // 7. W_O + residual(h) + LN1 + BN1 -> h2
  k_gemm_ln<128><<<nrb, 128, 0, stream>>>(Tb, W_O, b_O, h_, ln1g, ln1b, bn1g, bn1b, h2, N_);

  // 8. FFN1 (ReLU) — overwrites CSR scratch (dead by now)
  k_gemm_bias<128, 256, true><<<nrb, 256, 0, stream>>>(h2, W_f1, b_f1, hid, N_);

  // 9. FFN2 + residual(h2) + LN2 + BN2 -> out
  k_gemm_ln<256><<<nrb, 128, 0, stream>>>(hid, W_f2, b_f2, h2, ln2g, ln2b, bn2g, bn2b, out, N_);
}